// Round 4
// baseline (337.735 us; speedup 1.0000x reference)
//
#include <hip/hip_runtime.h>
#include <stdint.h>

// Problem dims
#define BDIM 8
#define CDIM 32
#define NDIM 512
#define TDIM 168
#define KG   2048          // GEMM K = 4 slices * 512 nodes
#define NJ   43008         // 256 (b,o) * 168 l
#define ALPHA_ 0.05f
#define BETA_  0.95f

typedef __attribute__((ext_vector_type(8))) short short8;
typedef __attribute__((ext_vector_type(4))) float f32x4;
typedef __attribute__((ext_vector_type(4))) float f4v;
typedef __attribute__((ext_vector_type(4))) unsigned short u16x4;

__device__ __forceinline__ unsigned short f2bf(float f) {
  union { float f; unsigned int u; } v; v.f = f;
  unsigned int r = v.u + 0x7fffu + ((v.u >> 16) & 1u);
  return (unsigned short)(r >> 16);
}
__device__ __forceinline__ float bf2f(unsigned short h) {
  union { unsigned int u; float f; } v; v.u = ((unsigned int)h) << 16;
  return v.f;
}
__device__ __forceinline__ void gload_lds16(const void* g, void* l) {
  __builtin_amdgcn_global_load_lds((const __attribute__((address_space(1))) void*)g,
                                   (__attribute__((address_space(3))) void*)l, 16, 0, 0);
}

// ---- prep: row sums of (adp + I) and (adp^T + I) ----
__global__ void gc_prep(const float* __restrict__ adp, float* __restrict__ rs) {
  int v = blockIdx.x, t = threadIdx.x;
  float sA = 0.f, sB = 0.f;
  for (int w = t; w < NDIM; w += 256) { sA += adp[v * NDIM + w]; sB += adp[w * NDIM + v]; }
  __shared__ float red[2][256];
  red[0][t] = sA; red[1][t] = sB; __syncthreads();
  for (int s = 128; s > 0; s >>= 1) {
    if (t < s) { red[0][t] += red[0][t + s]; red[1][t] += red[1][t + s]; }
    __syncthreads();
  }
  if (t == 0) { rs[v] = 1.f + red[0][0]; rs[NDIM + v] = 1.f + red[1][0]; }
}

// ---- build A (slice 0) and A' (slice 2) into chunked G2[(k>>3)][n][8], plus fp32 copies ----
__global__ void gc_build(const float* __restrict__ adp, const float* __restrict__ rs,
                         float* __restrict__ Af, unsigned short* __restrict__ G2) {
  int v = blockIdx.x, t = threadIdx.x;
  float ra = 1.f / rs[v], rb = 1.f / rs[NDIM + v];
  for (int w = t; w < NDIM; w += 256) {
    float d = (v == w) ? 1.f : 0.f;
    float a  = (adp[v * NDIM + w] + d) * ra;   // A[v][w]
    float a2 = (adp[w * NDIM + v] + d) * rb;   // A'[v][w]
    Af[(size_t)v * NDIM + w] = a;
    Af[(size_t)NDIM * NDIM + (size_t)v * NDIM + w] = a2;
    G2[(size_t)(((0 * 64) + (w >> 3)) * 512 + v) * 8 + (w & 7)] = f2bf(a);
    G2[(size_t)(((2 * 64) + (w >> 3)) * 512 + v) * 8 + (w & 7)] = f2bf(a2);
  }
}

// ---- A^2 (slice 1) and A'^2 (slice 3) into G2 ----
__global__ void gc_sq(const float* __restrict__ Af, unsigned short* __restrict__ G2) {
  int mat = blockIdx.x >> 6, tile = blockIdx.x & 63;
  int v0 = (tile >> 3) * 64, w0 = (tile & 7) * 64;
  const float* M = Af + (size_t)mat * NDIM * NDIM;
  __shared__ float T1[64][64];
  __shared__ float T2[64][65];
  int t = threadIdx.x;
  float acc[4][4] = {};
  for (int u0 = 0; u0 < NDIM; u0 += 64) {
    for (int idx = t; idx < 64 * 64; idx += 256) {
      int r = idx >> 6, c2 = idx & 63;
      T1[r][c2] = M[(size_t)(v0 + r) * NDIM + u0 + c2];
      T2[r][c2] = M[(size_t)(u0 + r) * NDIM + w0 + c2];
    }
    __syncthreads();
    int ty = t >> 4, tx = t & 15;
    for (int u = 0; u < 64; ++u) {
      float b0 = T2[u][tx * 4], b1v = T2[u][tx * 4 + 1], b2v = T2[u][tx * 4 + 2], b3v = T2[u][tx * 4 + 3];
      #pragma unroll
      for (int i = 0; i < 4; ++i) {
        float a = T1[ty * 4 + i][u];
        acc[i][0] += a * b0; acc[i][1] += a * b1v; acc[i][2] += a * b2v; acc[i][3] += a * b3v;
      }
    }
    __syncthreads();
  }
  int ty = t >> 4, tx = t & 15;
  int sl = mat ? 3 : 1;
  for (int i = 0; i < 4; ++i)
    for (int j = 0; j < 4; ++j) {
      int v = v0 + ty * 4 + i, w = w0 + tx * 4 + j;
      G2[(size_t)((sl * 64 + (w >> 3)) * 512 + v) * 8 + (w & 7)] = f2bf(acc[i][j]);
    }
}

// ---- folded channel-mix matrices, bf16: Ub[160][32] rows = {U1,U2,V1,V2,U0'}; bias = b1+b2 ----
__global__ void gc_ucat(const float* __restrict__ W1, const float* __restrict__ b1,
                        const float* __restrict__ W2, const float* __restrict__ b2,
                        unsigned short* __restrict__ Ub, float* __restrict__ bias) {
  int t = threadIdx.x;
  for (int idx = t; idx < 160 * 32; idx += 256) {
    int ko = idx >> 5, c = idx & 31, o = ko & 31, s = ko >> 5;
    float v;
    if (s == 0)      v = BETA_ * (W1[o * 96 + 32 + c] + ALPHA_ * W1[o * 96 + 64 + c]);
    else if (s == 1) v = BETA_ * BETA_ * W1[o * 96 + 64 + c];
    else if (s == 2) v = BETA_ * (W2[o * 96 + 32 + c] + ALPHA_ * W2[o * 96 + 64 + c]);
    else if (s == 3) v = BETA_ * BETA_ * W2[o * 96 + 64 + c];
    else             v = W1[o * 96 + c] + ALPHA_ * (W1[o * 96 + 32 + c] + W1[o * 96 + 64 + c])
                       + W2[o * 96 + c] + ALPHA_ * (W2[o * 96 + 32 + c] + W2[o * 96 + 64 + c]);
    Ub[idx] = f2bf(v);
  }
  if (t < 32) bias[t] = b1[t] + b2[t];
}

// ---- channel-mix via MFMA (pos-as-row) + LDS transpose: 16B global writes ----
// grid 1024 = 8 b * 64 wtiles(8 nodes) * 2 l-halves(80/88); 512 threads (8 waves)
__global__ __launch_bounds__(512, 4) void gc_mix4(const float* __restrict__ x,
    const unsigned short* __restrict__ Ub, unsigned short* __restrict__ Pg,
    unsigned short* __restrict__ R0) {
  __shared__ __align__(16) unsigned short xT[704 * 40];  // [pos][c pad 40] bf16, 56.3KB
  __shared__ __align__(16) unsigned short Tb[16 * 712];  // [o16][pos], 22.8KB
  int bid = blockIdx.x;
  int h = bid & 1, wt = (bid >> 1) & 63, b = bid >> 7;
  int L = h ? 88 : 80, l0 = h * 80, w0 = wt * 8;
  int NF4 = L >> 2;            // float4 per (c,w) row: 20 / 22
  int NT = L >> 1;             // 16-pos col tiles: 40 / 44
  int tid = threadIdx.x, wv = tid >> 6;
  int lane = tid & 63, l15 = lane & 15, hi = lane >> 4;

  // stage x[b][:][w0..w0+8)[l0..l0+L) -> xT[pos][c] transposed bf16
  int iters = (8 * NF4 * 32) >> 9;   // 10 / 11, exact
  for (int q = 0; q < iters; ++q) {
    int f = q * 512 + tid;
    int c = f / (8 * NF4);
    int rem = f - c * 8 * NF4;
    int w = rem / NF4, l4 = rem - w * NF4;
    f4v v = *(const f4v*)(x + (size_t)((b * 32 + c) * 512 + w0 + w) * 168 + l0 + l4 * 4);
    int pos = w * L + l4 * 4;
    xT[(pos    ) * 40 + c] = f2bf(v[0]);
    xT[(pos + 1) * 40 + c] = f2bf(v[1]);
    xT[(pos + 2) * 40 + c] = f2bf(v[2]);
    xT[(pos + 3) * 40 + c] = f2bf(v[3]);
  }
  __syncthreads();

  // B-operand fragments from Ub (col=o=l15, k=hi*8..+8) -- layout verified r2/r3
  short8 uF[10];
  #pragma unroll
  for (int mt = 0; mt < 10; ++mt)
    uF[mt] = *(const short8*)(Ub + (size_t)(mt * 16 + l15) * 32 + hi * 8);

  // A-operand fragments from xT (row=pos=ct*16+l15, k=hi*8..+8), reused over all mt
  short8 xf[6];
  #pragma unroll
  for (int i = 0; i < 6; ++i) {
    int ct = wv + 8 * i;
    if (ct < NT)
      xf[i] = *(const short8*)&xT[(ct * 16 + l15) * 40 + hi * 8];
  }

  for (int mt = 0; mt < 10; ++mt) {
    // compute: C[pos-row, o-col]; lane holds o=l15, pos=ct*16+hi*4+r (r consecutive)
    #pragma unroll
    for (int i = 0; i < 6; ++i) {
      int ct = wv + 8 * i;
      if (ct < NT) {
        f32x4 z = {0.f, 0.f, 0.f, 0.f};
        f32x4 p = __builtin_amdgcn_mfma_f32_16x16x32_bf16(xf[i], uF[mt], z, 0, 0, 0);
        u16x4 pk = { f2bf(p[0]), f2bf(p[1]), f2bf(p[2]), f2bf(p[3]) };
        *(u16x4*)&Tb[l15 * 712 + ct * 16 + hi * 4] = pk;   // one 8B write per MFMA
      }
    }
    __syncthreads();
    // coalesced 16B global read-out
    if (mt < 8) {
      int s = mt >> 1, ohi = (mt & 1) << 4;
      size_t kbg = (size_t)(s * 64 + wt);
      int total = 16 * L;
      #pragma unroll
      for (int k = 0; k < 3; ++k) {
        int chunk = tid + 512 * k;
        if (chunk < total) {
          int o16 = chunk / L, ll = chunk - o16 * L;
          short8 vv;
          #pragma unroll
          for (int w = 0; w < 8; ++w)
            vv[w] = (short)Tb[o16 * 712 + w * L + ll];
          *(short8*)(Pg + (kbg * NJ + (size_t)(b * 32 + ohi + o16) * 168 + l0 + ll) * 8) = vv;
        }
      }
    } else {
      int ohi = (mt & 1) << 4;
      int lgc = L >> 3;                   // 10 / 11
      int total = 128 * lgc;
      #pragma unroll
      for (int k = 0; k < 3; ++k) {
        int chunk = tid + 512 * k;
        if (chunk < total) {
          int o16 = chunk / (lgc * 8);
          int rem = chunk - o16 * lgc * 8;
          int w = rem / lgc, lg = rem - w * lgc;
          short8 vv = *(const short8*)&Tb[o16 * 712 + w * L + lg * 8];
          *(short8*)(R0 + ((size_t)(b * 32 + ohi + o16) * 512 + w0 + w) * 168 + l0 + lg * 8) = vv;
        }
      }
    }
    __syncthreads();
  }
}

// ---- main GEMM: C[512 n][43008 j] = G[512][2048] * P[2048][43008], + R0 + bias ----
// 448 blocks (2 mt * 224 jt), 512 threads = 8 waves (2M x 4N), wave tile 128x48
// BM=256 BN=192 BK=64; A 2-buf + B 3-buf LDS (136KB); 1 barrier/iter; vmcnt(3).
__global__ __launch_bounds__(512, 2) void gc_gemm4(const unsigned short* __restrict__ G2,
    const unsigned short* __restrict__ Pg, const unsigned short* __restrict__ R0,
    const float* __restrict__ bias, float* __restrict__ out) {
  int bid = blockIdx.x;
  int swz = (bid & 7) * 56 + (bid >> 3);   // XCD-chunked bijective swizzle (448 = 8*56)
  int mt = swz & 1, jt = swz >> 1;         // mt fastest: B-panel pair adjacent on same XCD
  int n0 = mt * 256, j0 = jt * 192;

  __shared__ __align__(16) unsigned short Ab[2][16384];  // [kb 8][n 256][8]
  __shared__ __align__(16) unsigned short Bb[3][12288];  // [kb 8][j 192][8]
  int tid = threadIdx.x, lane = tid & 63, wid = tid >> 6;
  int wm = wid >> 2, wn = wid & 3;
  int l15 = lane & 15, hi = lane >> 4;

  // staging assignments (16B chunks)
  const unsigned short* srcA[4]; int dA[4];
  #pragma unroll
  for (int q = 0; q < 4; ++q) {
    int f = q * 512 + tid;
    srcA[q] = G2 + ((size_t)(f >> 8) * 512 + n0 + (f & 255)) * 8;
    dA[q] = f * 8;
  }
  const unsigned short* srcB[3]; int dB[3];
  #pragma unroll
  for (int q = 0; q < 3; ++q) {
    int g = q * 512 + tid;
    int kb = g / 192, j = g - kb * 192;
    srcB[q] = Pg + ((size_t)kb * NJ + j0 + j) * 8;
    dB[q] = g * 8;
  }
  const size_t strideA = 8 * 512 * 8;          // shorts per K-tile
  const size_t strideB = (size_t)8 * NJ * 8;

  f32x4 acc[8][3] = {};

  // prologue: A(0)->buf0, B(0)->b0, B(1)->b1   (10 loads)
  #pragma unroll
  for (int q = 0; q < 4; ++q) gload_lds16(srcA[q], &Ab[0][dA[q]]);
  #pragma unroll
  for (int q = 0; q < 3; ++q) gload_lds16(srcB[q], &Bb[0][dB[q]]);
  #pragma unroll
  for (int q = 0; q < 3; ++q) gload_lds16(srcB[q] + strideB, &Bb[1][dB[q]]);

  int bb = 0;                                   // B read-buffer (kt % 3)
  for (int kt = 0; kt < 32; ++kt) {
    // drain A(kt), B(kt); keep B(kt+1) in flight
    if (kt < 31) asm volatile("s_waitcnt vmcnt(3)" ::: "memory");
    else         asm volatile("s_waitcnt vmcnt(0)" ::: "memory");
    __builtin_amdgcn_s_barrier();               // all threads' tile-kt loads landed
    __builtin_amdgcn_sched_barrier(0);

    // prefetch: A one ahead (L2-hot), B two ahead (L3-latency slack = 2 iters)
    if (kt + 1 < 32) {
      #pragma unroll
      for (int q = 0; q < 4; ++q)
        gload_lds16(srcA[q] + (size_t)(kt + 1) * strideA, &Ab[(kt + 1) & 1][dA[q]]);
    }
    if (kt + 2 < 32) {
      int bt = (bb == 0) ? 2 : bb - 1;          // (bb+2)%3
      #pragma unroll
      for (int q = 0; q < 3; ++q)
        gload_lds16(srcB[q] + (size_t)(kt + 2) * strideB, &Bb[bt][dB[q]]);
    }

    const unsigned short* ap = Ab[kt & 1];
    const unsigned short* bp = Bb[bb];
    #pragma unroll
    for (int kc = 0; kc < 2; ++kc) {
      short8 aF[8], bF[3];
      #pragma unroll
      for (int mi = 0; mi < 8; ++mi)
        aF[mi] = *(const short8*)&ap[(kc * 4 + hi) * 2048 + (wm * 128 + mi * 16 + l15) * 8];
      #pragma unroll
      for (int nj = 0; nj < 3; ++nj)
        bF[nj] = *(const short8*)&bp[(kc * 4 + hi) * 1536 + (wn * 48 + nj * 16 + l15) * 8];
      __builtin_amdgcn_s_setprio(1);
      #pragma unroll
      for (int mi = 0; mi < 8; ++mi)
        #pragma unroll
        for (int nj = 0; nj < 3; ++nj)
          acc[mi][nj] = __builtin_amdgcn_mfma_f32_16x16x32_bf16(aF[mi], bF[nj], acc[mi][nj], 0, 0, 0);
      __builtin_amdgcn_s_setprio(0);
    }
    bb = (bb == 2) ? 0 : bb + 1;
  }

  // epilogue: out[(bo*512+n)*168+l] = acc + R0 + bias[o]
  #pragma unroll
  for (int nj = 0; nj < 3; ++nj) {
    int jj = j0 + wn * 48 + nj * 16 + l15;
    int bo = jj / 168;
    int l = jj - bo * 168;
    float bs = bias[bo & 31];
    size_t obase = (size_t)bo * 86016 + l;
    #pragma unroll
    for (int mi = 0; mi < 8; ++mi) {
      #pragma unroll
      for (int r = 0; r < 4; ++r) {
        int n = n0 + wm * 128 + mi * 16 + hi * 4 + r;
        size_t idx = obase + (size_t)n * 168;
        out[idx] = acc[mi][nj][r] + bf2f(R0[idx]) + bs;
      }
    }
  }
}

extern "C" void kernel_launch(void* const* d_in, const int* in_sizes, int n_in,
                              void* d_out, int out_size, void* d_ws, size_t ws_size,
                              hipStream_t stream) {
  const float* x   = (const float*)d_in[0];
  const float* adp = (const float*)d_in[1];
  const float* W1  = (const float*)d_in[2];
  const float* b1  = (const float*)d_in[3];
  const float* W2  = (const float*)d_in[4];
  const float* b2  = (const float*)d_in[5];
  float* out = (float*)d_out;

  char* w = (char*)d_ws;
  unsigned short* Pg  = (unsigned short*)(w);                  // 176,160,768 B
  unsigned short* R0  = (unsigned short*)(w + 176160768ULL);   //  44,040,192 B
  unsigned short* G2  = (unsigned short*)(w + 220200960ULL);   //   2,097,152 B
  float* Af           = (float*)(w + 222298112ULL);            //   2,097,152 B
  float* rs           = (float*)(w + 224395264ULL);            //       4,096 B
  unsigned short* Ub  = (unsigned short*)(w + 224399360ULL);   //      16,384 B (10,240 used)
  float* bias         = (float*)(w + 224415744ULL);            //         128 B
  if (ws_size < 224415872ULL) return;                          // need ~214 MiB

  gc_prep<<<512, 256, 0, stream>>>(adp, rs);
  gc_build<<<512, 256, 0, stream>>>(adp, rs, Af, G2);
  gc_sq<<<128, 256, 0, stream>>>(Af, G2);
  gc_ucat<<<1, 256, 0, stream>>>(W1, b1, W2, b2, Ub, bias);
  gc_mix4<<<1024, 512, 0, stream>>>(x, Ub, Pg, R0);
  gc_gemm4<<<448, 512, 0, stream>>>(G2, Pg, R0, bias, out);
}